// Round 5
// baseline (260.105 us; speedup 1.0000x reference)
//
#include <hip/hip_runtime.h>

// YOLO loss, forward only. pred/target: (16384, 7, 7, 30) fp32, out: scalar fp32.
// S=7, B=2, CLS=20, N=30, LAMBDA_COORD=5, LAMBDA_NOOBJ=0.5, BATCH=16384.
// NOTE: reference conf_loc = arange(B)*B+4 = [4,6] (not [4,9]) — mirrored here.
//
// R6: R5 + non-temporal loads (nt cache-bypass). History:
//   R1 register-direct float2 scattered:   75us @ 64% occ
//   R2 global_load_lds DMA:                75us @  4% occ
//   R3 reg-staged LDS + barrier:         73.5us @ 14% occ
//   R4 cond. prefetch regs -> scratch:    100us (WRITE_SIZE 168 MB, rule #20)
//   R5 straight-line float4 pairs:         75us @ 29% occ, VGPR 64, clean
// Four structures x occupancy 4-64% all deliver exactly 2.57 TB/s with no
// saturated counter -> delivery-path ceiling, not issue-side. FETCH=94 MB of
// 193 MB demand: half the stream hits L3 (193 MB footprint ~ L3 capacity).
// R6 discriminates the two surviving theories: (a) per-CU miss-queue cap
// (nt changes nothing) vs (b) L3-hit/fill path is the slow component
// (nt streams everything from HBM read path -> ~2x). One-line change vs R5.

typedef float v4f __attribute__((ext_vector_type(4)));

#define TPB 256
#define R_TOTAL (16384 * 7 * 7)       // 802816 cells
#define NPAIRS (R_TOTAL / 2)          // 401408 pairs
#define GRID (NPAIRS / TPB)           // 1568 blocks

// element j (0..59) of the pair record held in a v4f[15] array; j must be a
// compile-time constant so every access is a register, never scratch.
#define EL(a, j) (a[(j) >> 2][(j) & 3])

// loss for one cell at float offset OFS (0 or 30) within the pair record.
#define CELL_LOSS(OFS) do {                                                   \
    const float t4v = EL(t4, (OFS) + 4);                                      \
    if (t4v == 0.0f) {                                                        \
        float d4 = EL(p4, (OFS) + 4) - t4v;                                   \
        float d6 = EL(p4, (OFS) + 6) - EL(t4, (OFS) + 6);                     \
        sum += 0.5f * (d4 * d4 + d6 * d6);                                    \
    } else if (t4v == 1.0f) {                                                 \
        float tx1 = EL(t4,(OFS)+0) - EL(t4,(OFS)+2) * 0.5f;                   \
        float ty1 = EL(t4,(OFS)+1) - EL(t4,(OFS)+3) * 0.5f;                   \
        float tx2 = EL(t4,(OFS)+0) + EL(t4,(OFS)+2) * 0.5f;                   \
        float ty2 = EL(t4,(OFS)+1) + EL(t4,(OFS)+3) * 0.5f;                   \
        float area2 = (tx2 - tx1) * (ty2 - ty1);                              \
        float ax1 = EL(p4,(OFS)+0) - EL(p4,(OFS)+2) * 0.5f;                   \
        float ay1 = EL(p4,(OFS)+1) - EL(p4,(OFS)+3) * 0.5f;                   \
        float ax2 = EL(p4,(OFS)+0) + EL(p4,(OFS)+2) * 0.5f;                   \
        float ay2 = EL(p4,(OFS)+1) + EL(p4,(OFS)+3) * 0.5f;                   \
        float w0 = fmaxf(fminf(ax2, tx2) - fmaxf(ax1, tx1), 0.0f);            \
        float h0 = fmaxf(fminf(ay2, ty2) - fmaxf(ay1, ty1), 0.0f);            \
        float inter0 = w0 * h0;                                               \
        float uni0 = (ax2 - ax1) * (ay2 - ay1) + area2 - inter0;              \
        float iou0 = (uni0 > 0.0f) ? (inter0 / uni0) : 0.0f;                  \
        float bx1 = EL(p4,(OFS)+5) - EL(p4,(OFS)+7) * 0.5f;                   \
        float by1 = EL(p4,(OFS)+6) - EL(p4,(OFS)+8) * 0.5f;                   \
        float bx2 = EL(p4,(OFS)+5) + EL(p4,(OFS)+7) * 0.5f;                   \
        float by2 = EL(p4,(OFS)+6) + EL(p4,(OFS)+8) * 0.5f;                   \
        float w1 = fmaxf(fminf(bx2, tx2) - fmaxf(bx1, tx1), 0.0f);            \
        float h1 = fmaxf(fminf(by2, ty2) - fmaxf(by1, ty1), 0.0f);            \
        float inter1 = w1 * h1;                                               \
        float uni1 = (bx2 - bx1) * (by2 - by1) + area2 - inter1;              \
        float iou1 = (uni1 > 0.0f) ? (inter1 / uni1) : 0.0f;                  \
        bool j1 = (iou1 > iou0);                                              \
        float max_iou = fmaxf(iou0, iou1);                                    \
        float r0 = j1 ? EL(p4,(OFS)+5) : EL(p4,(OFS)+0);                      \
        float r1 = j1 ? EL(p4,(OFS)+6) : EL(p4,(OFS)+1);                      \
        float r2 = j1 ? EL(p4,(OFS)+7) : EL(p4,(OFS)+2);                      \
        float r3 = j1 ? EL(p4,(OFS)+8) : EL(p4,(OFS)+3);                      \
        float r4 = j1 ? EL(p4,(OFS)+9) : EL(p4,(OFS)+4);                      \
        float dx = r0 - EL(t4,(OFS)+0);                                       \
        float dy = r1 - EL(t4,(OFS)+1);                                       \
        float sw = sqrtf(fmaxf(r2, 0.0f)) - sqrtf(fmaxf(EL(t4,(OFS)+2), 0.0f));\
        float sh = sqrtf(fmaxf(r3, 0.0f)) - sqrtf(fmaxf(EL(t4,(OFS)+3), 0.0f));\
        float coord = dx * dx + dy * dy + sw * sw + sh * sh;                  \
        float dc = r4 - max_iou;                                              \
        float cls = 0.0f;                                                     \
        _Pragma("unroll")                                                     \
        for (int k = 10; k < 30; k++) {                                       \
            float d = EL(p4,(OFS)+k) - EL(t4,(OFS)+k);                        \
            cls += d * d;                                                     \
        }                                                                     \
        sum += 5.0f * coord + dc * dc + cls;                                  \
    }                                                                         \
} while (0)
// (t4 guaranteed in {0,1} by setup; other values contribute 0, matching ref)

__global__ __launch_bounds__(TPB) void yolo_loss_kernel(
    const float* __restrict__ pred, const float* __restrict__ target,
    float* __restrict__ out)
{
    __shared__ float red[TPB / 64];

    const int tid = threadIdx.x;
    const size_t pair = (size_t)blockIdx.x * TPB + tid;

    // 30 straight-line NON-TEMPORAL dwordx4 loads: nt bit bypasses L2/L3
    // allocation -> full stream from the HBM read path (theory H2).
    const v4f* gp = (const v4f*)(pred + pair * 60);
    const v4f* gt = (const v4f*)(target + pair * 60);
    v4f p4[15], t4[15];
    #pragma unroll
    for (int k = 0; k < 15; k++) p4[k] = __builtin_nontemporal_load(&gp[k]);
    #pragma unroll
    for (int k = 0; k < 15; k++) t4[k] = __builtin_nontemporal_load(&gt[k]);

    float sum = 0.0f;
    CELL_LOSS(0);    // cell A: floats [0,30)
    CELL_LOSS(30);   // cell B: floats [30,60)

    // wave-64 shfl reduction, 4 partials via LDS, one atomic per block
    #pragma unroll
    for (int off = 32; off > 0; off >>= 1)
        sum += __shfl_down(sum, off, 64);
    if ((tid & 63) == 0) red[tid >> 6] = sum;
    __syncthreads();
    if (tid == 0) {
        float s = red[0] + red[1] + red[2] + red[3];
        atomicAdd(out, s * (1.0f / 16384.0f));
    }
}

extern "C" void kernel_launch(void* const* d_in, const int* in_sizes, int n_in,
                              void* d_out, int out_size, void* d_ws, size_t ws_size,
                              hipStream_t stream) {
    const float* pred = (const float*)d_in[0];
    const float* target = (const float*)d_in[1];
    float* out = (float*)d_out;
    // d_out is poisoned with 0xAA before every launch; we accumulate into it.
    hipMemsetAsync(out, 0, sizeof(float), stream);
    yolo_loss_kernel<<<GRID, TPB, 0, stream>>>(pred, target, out);
}

// Round 7
// 212.975 us; speedup vs baseline: 1.2213x; 1.2213x over previous
//
#include <hip/hip_runtime.h>

// YOLO loss, forward only. pred/target: (16384, 7, 7, 30) fp32, out: scalar fp32.
// S=7, B=2, CLS=20, N=30, LAMBDA_COORD=5, LAMBDA_NOOBJ=0.5, BATCH=16384.
// NOTE: reference conf_loc = arange(B)*B+4 = [4,6] (not [4,9]) — mirrored here.
//
// R7b: conditional byte reduction (resubmit of R7 — prior round failed in
// the harness container, no kernel signal). History:
//   R1 scattered float2 @64% occ:          75us   delivered 2.57 TB/s
//   R2 global_load_lds DMA @4% occ:        75us   delivered 2.57 TB/s
//   R3 reg-staged LDS+barrier @14% occ:  73.5us   delivered 2.62 TB/s
//   R4 cond. loop-carried prefetch:       100us   (scratch, rule #20)
//   R5 straight-line float4 @29% occ:      75us   delivered 2.57 TB/s
//   R6 R5+nontemporal:                    107us   (L3 bypass: strictly worse)
// Invariant: CU-delivered bytes/time = 2.57 TB/s regardless of structure,
// occupancy, request count, or HBM/L3 split -> the throttle scales with
// DELIVERED BYTES. Lever: 85% of cells need only p[4],p[6],t[4],t[6].
// Per 240 B pair-record: always load 48 B of headers (1 dwordx4 @byte16 for
// cell A, 1 dwordx4 @byte128 + 1 dwordx2 @byte144 for cell B, per array);
// exec-masked full load (30 dwordx4) only for the ~27.75% of pairs with an
// obj cell. Avg ~196 B/pair vs 480 -> 2.4x fewer delivered bytes.
// Header regs + full-record arrays are branch-local with constant indices
// (no loop-carried conditional state -> no scratch; WRITE_SIZE verifies).

typedef float v4f __attribute__((ext_vector_type(4)));
typedef float v2f __attribute__((ext_vector_type(2)));

#define TPB 256
#define R_TOTAL (16384 * 7 * 7)       // 802816 cells
#define NPAIRS (R_TOTAL / 2)          // 401408 pairs
#define GRID (NPAIRS / TPB)           // 1568 blocks

// element j (0..59) of a pair record held in a v4f[15]; j compile-time const.
#define EL(a, j) (a[(j) >> 2][(j) & 3])

// obj-cell loss (t4==1 established by caller) at float offset OFS (0 or 30).
#define OBJ_LOSS(P, T, OFS) do {                                              \
    float tx1 = EL(T,(OFS)+0) - EL(T,(OFS)+2) * 0.5f;                         \
    float ty1 = EL(T,(OFS)+1) - EL(T,(OFS)+3) * 0.5f;                         \
    float tx2 = EL(T,(OFS)+0) + EL(T,(OFS)+2) * 0.5f;                         \
    float ty2 = EL(T,(OFS)+1) + EL(T,(OFS)+3) * 0.5f;                         \
    float area2 = (tx2 - tx1) * (ty2 - ty1);                                  \
    float ax1 = EL(P,(OFS)+0) - EL(P,(OFS)+2) * 0.5f;                         \
    float ay1 = EL(P,(OFS)+1) - EL(P,(OFS)+3) * 0.5f;                         \
    float ax2 = EL(P,(OFS)+0) + EL(P,(OFS)+2) * 0.5f;                         \
    float ay2 = EL(P,(OFS)+1) + EL(P,(OFS)+3) * 0.5f;                         \
    float w0 = fmaxf(fminf(ax2, tx2) - fmaxf(ax1, tx1), 0.0f);                \
    float h0 = fmaxf(fminf(ay2, ty2) - fmaxf(ay1, ty1), 0.0f);                \
    float inter0 = w0 * h0;                                                   \
    float uni0 = (ax2 - ax1) * (ay2 - ay1) + area2 - inter0;                  \
    float iou0 = (uni0 > 0.0f) ? (inter0 / uni0) : 0.0f;                      \
    float bx1 = EL(P,(OFS)+5) - EL(P,(OFS)+7) * 0.5f;                         \
    float by1 = EL(P,(OFS)+6) - EL(P,(OFS)+8) * 0.5f;                         \
    float bx2 = EL(P,(OFS)+5) + EL(P,(OFS)+7) * 0.5f;                         \
    float by2 = EL(P,(OFS)+6) + EL(P,(OFS)+8) * 0.5f;                         \
    float w1 = fmaxf(fminf(bx2, tx2) - fmaxf(bx1, tx1), 0.0f);                \
    float h1 = fmaxf(fminf(by2, ty2) - fmaxf(by1, ty1), 0.0f);                \
    float inter1 = w1 * h1;                                                   \
    float uni1 = (bx2 - bx1) * (by2 - by1) + area2 - inter1;                  \
    float iou1 = (uni1 > 0.0f) ? (inter1 / uni1) : 0.0f;                      \
    bool j1 = (iou1 > iou0);                                                  \
    float max_iou = fmaxf(iou0, iou1);                                        \
    float r0 = j1 ? EL(P,(OFS)+5) : EL(P,(OFS)+0);                            \
    float r1 = j1 ? EL(P,(OFS)+6) : EL(P,(OFS)+1);                            \
    float r2 = j1 ? EL(P,(OFS)+7) : EL(P,(OFS)+2);                            \
    float r3 = j1 ? EL(P,(OFS)+8) : EL(P,(OFS)+3);                            \
    float r4 = j1 ? EL(P,(OFS)+9) : EL(P,(OFS)+4);                            \
    float dx = r0 - EL(T,(OFS)+0);                                            \
    float dy = r1 - EL(T,(OFS)+1);                                            \
    float sw = sqrtf(fmaxf(r2, 0.0f)) - sqrtf(fmaxf(EL(T,(OFS)+2), 0.0f));    \
    float sh = sqrtf(fmaxf(r3, 0.0f)) - sqrtf(fmaxf(EL(T,(OFS)+3), 0.0f));    \
    float coord = dx * dx + dy * dy + sw * sw + sh * sh;                      \
    float dc = r4 - max_iou;                                                  \
    float cls = 0.0f;                                                         \
    _Pragma("unroll")                                                         \
    for (int k = 10; k < 30; k++) {                                           \
        float d = EL(P,(OFS)+k) - EL(T,(OFS)+k);                              \
        cls += d * d;                                                         \
    }                                                                         \
    sum += 5.0f * coord + dc * dc + cls;                                      \
} while (0)

__global__ __launch_bounds__(TPB) void yolo_loss_kernel(
    const float* __restrict__ pred, const float* __restrict__ target,
    float* __restrict__ out)
{
    __shared__ float red[TPB / 64];

    const int tid = threadIdx.x;
    const size_t pair = (size_t)blockIdx.x * TPB + tid;
    const char* gp = (const char*)pred + pair * 240;
    const char* gt = (const char*)target + pair * 240;

    // ---- always-loaded headers: 48 B/pair/array ----
    // cell A: floats 4..7  = byte 16  (16B-aligned): [0]=f4(conf) [2]=f6
    // cell B: floats 32..35 = byte 128 (16B-aligned): [2]=f34(conf)
    //         floats 36..37 = byte 144 (8B-aligned):  [0]=f36
    v4f tA  = *(const v4f*)(gt + 16);
    v4f tB  = *(const v4f*)(gt + 128);
    v2f tB2 = *(const v2f*)(gt + 144);
    v4f pA  = *(const v4f*)(gp + 16);
    v4f pB  = *(const v4f*)(gp + 128);
    v2f pB2 = *(const v2f*)(gp + 144);

    float sum = 0.0f;
    const bool objA = (tA[0] == 1.0f);
    const bool objB = (tB[2] == 1.0f);

    if (tA[0] == 0.0f) {             // noobj cell A: conf_loc [4,6]
        float d4 = pA[0] - tA[0];
        float d6 = pA[2] - tA[2];
        sum += 0.5f * (d4 * d4 + d6 * d6);
    }
    if (tB[2] == 0.0f) {             // noobj cell B: floats 34, 36
        float d4 = pB[2] - tB[2];
        float d6 = pB2[0] - tB2[0];
        sum += 0.5f * (d4 * d4 + d6 * d6);
    }
    // (t4 guaranteed in {0,1} by setup; other values contribute 0, matching ref)

    if (objA | objB) {
        // exec-masked full-record load: only ~27.75% of lanes fetch these
        // lines. Branch-local arrays, constant indices -> registers.
        v4f P[15], T[15];
        const v4f* gp4 = (const v4f*)gp;
        const v4f* gt4 = (const v4f*)gt;
        #pragma unroll
        for (int k = 0; k < 15; k++) P[k] = gp4[k];
        #pragma unroll
        for (int k = 0; k < 15; k++) T[k] = gt4[k];
        if (objA) { OBJ_LOSS(P, T, 0); }
        if (objB) { OBJ_LOSS(P, T, 30); }
    }

    // wave-64 shfl reduction, 4 partials via LDS, one atomic per block
    #pragma unroll
    for (int off = 32; off > 0; off >>= 1)
        sum += __shfl_down(sum, off, 64);
    if ((tid & 63) == 0) red[tid >> 6] = sum;
    __syncthreads();
    if (tid == 0) {
        float s = red[0] + red[1] + red[2] + red[3];
        atomicAdd(out, s * (1.0f / 16384.0f));
    }
}

extern "C" void kernel_launch(void* const* d_in, const int* in_sizes, int n_in,
                              void* d_out, int out_size, void* d_ws, size_t ws_size,
                              hipStream_t stream) {
    const float* pred = (const float*)d_in[0];
    const float* target = (const float*)d_in[1];
    float* out = (float*)d_out;
    // d_out is poisoned with 0xAA before every launch; we accumulate into it.
    hipMemsetAsync(out, 0, sizeof(float), stream);
    yolo_loss_kernel<<<GRID, TPB, 0, stream>>>(pred, target, out);
}

// Round 8
// 204.532 us; speedup vs baseline: 1.2717x; 1.0413x over previous
//
#include <hip/hip_runtime.h>

// YOLO loss, forward only. pred/target: (16384, 7, 7, 30) fp32, out: scalar fp32.
// S=7, B=2, CLS=20, N=30, LAMBDA_COORD=5, LAMBDA_NOOBJ=0.5, BATCH=16384.
// NOTE: reference conf_loc = arange(B)*B+4 = [4,6] (not [4,9]) — mirrored here.
//
// R8 = R3 restored (best measured: 73.5 us dispatch / 204.2 us bench).
// Session conclusion — the ceiling is the per-XCD L2 LINE-FILL RATE:
//   ~1 x 128B line/cycle/XCD x 8 XCD x 2.4-2.5 GHz = 2.46-2.57 TB/s.
// Evidence: six structurally disjoint kernels (scattered float2 @64% occ,
// global_load_lds DMA @4%, reg-staged+LDS @14%, straight-line float4 @29%,
// nt-bypass, conditional byte-skip) ALL deliver 2.57-2.62 TB/s / ~75 us,
// invariant to occupancy, request count, access pattern, and HBM/L3 split;
// no SQ/TCC counter saturates (fill-port limits aren't counted). Byte-skip
// (R7b) didn't help because the per-cell conf fields (bytes +16..27 of every
// 120B record) touch every 128B line anyway -> line count is irreducible.
// Floor: 193 MB / 128 B = 1.51M lines / (8 x 2.45G lines/s) ~= 74-77 us.
// R3 measures 73.5 us. This is the roofline for any single-pass kernel here.
//
// Structure: each 256-thread block stages one 256-cell tile (61440 B) with
// fully-coalesced dwordx4 loads into registers, writes a linear LDS image,
// one barrier, then per-cell compute from LDS. 2 blocks/CU.

#define TPB 256
#define CB 30720                      // bytes per array per tile (256*120)
#define GRID 3136                     // 802816 cells / 256

__global__ __launch_bounds__(TPB, 2) void yolo_loss_kernel(
    const float* __restrict__ pred, const float* __restrict__ target,
    float* __restrict__ out)
{
    // [0, CB): pred tile, [CB, 2*CB): target tile — linear byte image.
    __shared__ __align__(16) unsigned char smem[2 * CB];   // 61440 B
    __shared__ float red[TPB / 64];

    const int tid = threadIdx.x;
    const size_t base = (size_t)blockIdx.x * CB;           // byte offset per array

    // ---- stage: coalesced global -> regs -> linear LDS image ----
    // Per array: 7 x dwordx4 (lane stride 16 B) + 1 x dwordx2 (lane stride 8 B)
    // covers 7*4096 + 2048 = 30720 B. All lanes contiguous -> perfect coalescing.
    const char* gp = (const char*)pred + base;
    const char* gt = (const char*)target + base;
    float4 vp[7], vt[7];
    float2 wp, wt;
    #pragma unroll
    for (int i = 0; i < 7; i++) vp[i] = *(const float4*)(gp + i * 4096 + tid * 16);
    wp = *(const float2*)(gp + 28672 + tid * 8);
    #pragma unroll
    for (int i = 0; i < 7; i++) vt[i] = *(const float4*)(gt + i * 4096 + tid * 16);
    wt = *(const float2*)(gt + 28672 + tid * 8);

    #pragma unroll
    for (int i = 0; i < 7; i++) *(float4*)(smem + i * 4096 + tid * 16) = vp[i];
    *(float2*)(smem + 28672 + tid * 8) = wp;
    #pragma unroll
    for (int i = 0; i < 7; i++) *(float4*)(smem + CB + i * 4096 + tid * 16) = vt[i];
    *(float2*)(smem + CB + 28672 + tid * 8) = wt;
    __syncthreads();

    // ---- compute: thread tid owns cell tid ----
    const float* pf = (const float*)(smem) + tid * 30;
    const float* tf = (const float*)(smem + CB) + tid * 30;

    float sum = 0.0f;
    const float t4 = tf[4];
    if (t4 == 0.0f) {
        // noobj: 0.5 * sum over conf_loc=[4,6] of (p-t)^2
        float d4 = pf[4] - t4;
        float d6 = pf[6] - tf[6];
        sum = 0.5f * (d4 * d4 + d6 * d6);
    } else if (t4 == 1.0f) {
        // target box -> xyxy (mirror reference float op order)
        float tx1 = tf[0] - tf[2] * 0.5f, ty1 = tf[1] - tf[3] * 0.5f;
        float tx2 = tf[0] + tf[2] * 0.5f, ty2 = tf[1] + tf[3] * 0.5f;
        float area2 = (tx2 - tx1) * (ty2 - ty1);

        // box 0
        float ax1 = pf[0] - pf[2] * 0.5f, ay1 = pf[1] - pf[3] * 0.5f;
        float ax2 = pf[0] + pf[2] * 0.5f, ay2 = pf[1] + pf[3] * 0.5f;
        float w0 = fmaxf(fminf(ax2, tx2) - fmaxf(ax1, tx1), 0.0f);
        float h0 = fmaxf(fminf(ay2, ty2) - fmaxf(ay1, ty1), 0.0f);
        float inter0 = w0 * h0;
        float uni0 = (ax2 - ax1) * (ay2 - ay1) + area2 - inter0;
        float iou0 = (uni0 > 0.0f) ? (inter0 / uni0) : 0.0f;

        // box 1
        float bx1 = pf[5] - pf[7] * 0.5f, by1 = pf[6] - pf[8] * 0.5f;
        float bx2 = pf[5] + pf[7] * 0.5f, by2 = pf[6] + pf[8] * 0.5f;
        float w1 = fmaxf(fminf(bx2, tx2) - fmaxf(bx1, tx1), 0.0f);
        float h1 = fmaxf(fminf(by2, ty2) - fmaxf(by1, ty1), 0.0f);
        float inter1 = w1 * h1;
        float uni1 = (bx2 - bx1) * (by2 - by1) + area2 - inter1;
        float iou1 = (uni1 > 0.0f) ? (inter1 / uni1) : 0.0f;

        // argmax over 2 -> first max index on ties
        bool j1 = (iou1 > iou0);
        float max_iou = fmaxf(iou0, iou1);
        // responsible box via per-element select (no dynamic indexing)
        float r0 = j1 ? pf[5] : pf[0];
        float r1 = j1 ? pf[6] : pf[1];
        float r2 = j1 ? pf[7] : pf[2];
        float r3 = j1 ? pf[8] : pf[3];
        float r4 = j1 ? pf[9] : pf[4];

        float dx = r0 - tf[0];
        float dy = r1 - tf[1];
        float sw = sqrtf(fmaxf(r2, 0.0f)) - sqrtf(fmaxf(tf[2], 0.0f));
        float sh = sqrtf(fmaxf(r3, 0.0f)) - sqrtf(fmaxf(tf[3], 0.0f));
        float coord = dx * dx + dy * dy + sw * sw + sh * sh;
        float dc = r4 - max_iou;

        float cls = 0.0f;
        #pragma unroll
        for (int k = 10; k < 30; k++) {
            float d = pf[k] - tf[k];
            cls += d * d;
        }
        sum = 5.0f * coord + dc * dc + cls;
    }
    // (t4 guaranteed in {0,1} by setup; other values contribute 0, matching ref)

    // ---- reduce: wave-64 shfl, then 4 partials via LDS, one atomic/block ----
    #pragma unroll
    for (int off = 32; off > 0; off >>= 1)
        sum += __shfl_down(sum, off, 64);
    if ((tid & 63) == 0) red[tid >> 6] = sum;
    __syncthreads();
    if (tid == 0) {
        float s = red[0] + red[1] + red[2] + red[3];
        atomicAdd(out, s * (1.0f / 16384.0f));
    }
}

extern "C" void kernel_launch(void* const* d_in, const int* in_sizes, int n_in,
                              void* d_out, int out_size, void* d_ws, size_t ws_size,
                              hipStream_t stream) {
    const float* pred = (const float*)d_in[0];
    const float* target = (const float*)d_in[1];
    float* out = (float*)d_out;
    // d_out is poisoned with 0xAA before every launch; we accumulate into it.
    hipMemsetAsync(out, 0, sizeof(float), stream);
    yolo_loss_kernel<<<GRID, TPB, 0, stream>>>(pred, target, out);
}